// Round 1
// baseline (760.073 us; speedup 1.0000x reference)
//
#include <hip/hip_runtime.h>
#include <math.h>

#define NEG_SLOPE 0.2f
#define GEPS 1e-5f

__device__ __forceinline__ float wave_reduce_sum(float v) {
#pragma unroll
    for (int o = 32; o > 0; o >>= 1) v += __shfl_down(v, o);
    return v;
}

// ---------------- edge_attr column sums ----------------
__global__ void k_ea_sum(const float* __restrict__ ea, float* __restrict__ ea_sum, int E) {
    const float2* ea2 = (const float2*)ea;
    float s0 = 0.f, s1 = 0.f;
    int stride = gridDim.x * blockDim.x;
    for (int e = blockIdx.x * blockDim.x + threadIdx.x; e < E; e += stride) {
        float2 v = ea2[e];
        s0 += v.x; s1 += v.y;
    }
    s0 = wave_reduce_sum(s0);
    s1 = wave_reduce_sum(s1);
    if ((threadIdx.x & 63) == 0) {
        atomicAdd(&ea_sum[0], s0);
        atomicAdd(&ea_sum[1], s1);
    }
}

// ---------------- CSR build ----------------
__global__ void k_deg(const int* __restrict__ dst, int* __restrict__ deg, int E) {
    int e = blockIdx.x * blockDim.x + threadIdx.x;
    if (e < E) atomicAdd(&deg[dst[e]], 1);
}

__global__ void k_scan1(const int* __restrict__ deg, int* __restrict__ row_ptr,
                        int* __restrict__ bsum, int N) {
    __shared__ int tmp[1024];
    int tid = threadIdx.x;
    int i = blockIdx.x * 1024 + tid;
    int v = (i < N) ? deg[i] : 0;
    tmp[tid] = v;
    __syncthreads();
#pragma unroll
    for (int off = 1; off < 1024; off <<= 1) {
        int t = (tid >= off) ? tmp[tid - off] : 0;
        __syncthreads();
        tmp[tid] += t;
        __syncthreads();
    }
    if (i < N) row_ptr[i + 1] = tmp[tid];
    if (tid == 1023) bsum[blockIdx.x] = tmp[1023];
}

__global__ void k_scan2(int* __restrict__ bsum, int nb) {
    __shared__ int tmp[1024];
    int tid = threadIdx.x;
    int v = (tid < nb) ? bsum[tid] : 0;
    tmp[tid] = v;
    __syncthreads();
#pragma unroll
    for (int off = 1; off < 1024; off <<= 1) {
        int t = (tid >= off) ? tmp[tid - off] : 0;
        __syncthreads();
        tmp[tid] += t;
        __syncthreads();
    }
    if (tid < nb) bsum[tid] = tmp[tid] - v;  // exclusive
}

__global__ void k_scan3(int* __restrict__ row_ptr, const int* __restrict__ bsum, int N) {
    int i = blockIdx.x * 1024 + threadIdx.x;
    if (i == 0) row_ptr[0] = 0;
    if (i < N) row_ptr[i + 1] += bsum[blockIdx.x];
}

__global__ void k_scatter(const int* __restrict__ dst, const int* __restrict__ row_ptr,
                          int* __restrict__ cursor, int* __restrict__ eid, int E) {
    int e = blockIdx.x * blockDim.x + threadIdx.x;
    if (e >= E) return;
    int d = dst[e];
    int pos = atomicAdd(&cursor[d], 1);
    eid[row_ptr[d] + pos] = e;
}

// ---------------- attention-edge constants ----------------
// C1[k*4+h] = sum_d We1[k*256 + h*64 + d] * ae1[h*64+d];   loopE1[h] = mean_ea . C1[:,h]
__global__ void k_consts(const float* __restrict__ We1, const float* __restrict__ ae1,
                         const float* __restrict__ We2, const float* __restrict__ ae2,
                         const float* __restrict__ ea_sum, int E,
                         float* __restrict__ C1, float* __restrict__ lE1,
                         float* __restrict__ C2, float* __restrict__ lE2) {
    int t = threadIdx.x, h = t >> 6, lane = t & 63;
    float p0 = We1[t] * ae1[t];
    float p1 = We1[256 + t] * ae1[t];
    p0 = wave_reduce_sum(p0);
    p1 = wave_reduce_sum(p1);
    if (lane == 0) { C1[h] = p0; C1[4 + h] = p1; }
    if (t < 128) {
        float q0 = We2[t] * ae2[t];
        float q1 = We2[128 + t] * ae2[t];
        q0 = wave_reduce_sum(q0);
        q1 = wave_reduce_sum(q1);
        if (lane == 0) { C2[h] = q0; C2[2 + h] = q1; }
    }
    __syncthreads();
    float m0 = ea_sum[0] / (float)E, m1 = ea_sum[1] / (float)E;
    if (t < 4) lE1[t] = m0 * C1[t] + m1 * C1[4 + t];
    if (t < 2) lE2[t] = m0 * C2[t] + m1 * C2[2 + t];
}

// ---------------- layer-1 node transform + attn dot ----------------
// block = 256 threads (4 waves = 4 heads), grid = N
__global__ void k_l1(const float* __restrict__ x, const float* __restrict__ W1,
                     const float* __restrict__ as1, const float* __restrict__ ad1,
                     float* __restrict__ h1, float* __restrict__ al_s, float* __restrict__ al_d) {
    int n = blockIdx.x, w = threadIdx.x >> 6, lane = threadIdx.x & 63, col = threadIdx.x;
    float x0 = x[3 * n], x1 = x[3 * n + 1], x2 = x[3 * n + 2];
    float hv = fmaf(x0, W1[col], fmaf(x1, W1[256 + col], x2 * W1[512 + col]));
    h1[(size_t)n * 256 + col] = hv;
    float ps = hv * as1[col], pd = hv * ad1[col];
    ps = wave_reduce_sum(ps);
    pd = wave_reduce_sum(pd);
    if (lane == 0) { al_s[n * 4 + w] = ps; al_d[n * 4 + w] = pd; }
}

// ---------------- attn dots for layer 2 (H=2), block = 128, grid = N ----------------
__global__ void k_al2(const float* __restrict__ hf, const float* __restrict__ as_,
                      const float* __restrict__ ad_, float* __restrict__ al_s,
                      float* __restrict__ al_d) {
    int n = blockIdx.x, w = threadIdx.x >> 6, lane = threadIdx.x & 63, col = threadIdx.x;
    float hv = hf[(size_t)n * 128 + col];
    float ps = hv * as_[col], pd = hv * ad_[col];
    ps = wave_reduce_sum(ps);
    pd = wave_reduce_sum(pd);
    if (lane == 0) { al_s[n * 2 + w] = ps; al_d[n * 2 + w] = pd; }
}

// ---------------- GAT aggregation: one wave per (node, head), online softmax ----------------
template <int H>
__global__ void k_agg(const float* __restrict__ hf, const float* __restrict__ al_s,
                      const float* __restrict__ al_d, const int* __restrict__ srcv,
                      const float* __restrict__ ea, const int* __restrict__ row_ptr,
                      const int* __restrict__ eid, const float* __restrict__ C,
                      const float* __restrict__ loopE, const float* __restrict__ bias,
                      float* __restrict__ out) {
    const int HD = H * 64;
    int n = blockIdx.x, h = threadIdx.x >> 6, lane = threadIdx.x & 63;
    float aln_s = al_s[n * H + h], aln_d = al_d[n * H + h];
    float C0 = C[h], C1v = C[H + h];
    // self loop first (src = dst = n)
    float lg = aln_s + aln_d + loopE[h];
    lg = (lg > 0.f) ? lg : lg * NEG_SLOPE;
    float m = lg, s = 1.f;
    float acc = hf[(size_t)n * HD + h * 64 + lane];
    int i0 = row_ptr[n], i1 = row_ptr[n + 1];
    for (int i = i0; i < i1; ++i) {
        int e = eid[i];
        int sn = srcv[e];
        float2 eav = *(const float2*)(ea + 2 * (size_t)e);
        float l = al_s[sn * H + h] + aln_d + eav.x * C0 + eav.y * C1v;
        l = (l > 0.f) ? l : l * NEG_SLOPE;
        float hv = hf[(size_t)sn * HD + h * 64 + lane];
        float mn = fmaxf(m, l);
        float sc = __expf(m - mn), wgt = __expf(l - mn);
        s = s * sc + wgt;
        acc = acc * sc + wgt * hv;
        m = mn;
    }
    out[(size_t)n * HD + h * 64 + lane] = acc / s + bias[h * 64 + lane];
}

// ---------------- GraphNorm: column stats ----------------
__global__ void k_stats(const float* __restrict__ x, float* __restrict__ stats, int rows) {
    int C = blockDim.x, col = threadIdx.x;
    float s = 0.f, s2 = 0.f;
    for (int r = blockIdx.x; r < rows; r += gridDim.x) {
        float v = x[(size_t)r * C + col];
        s += v;
        s2 = fmaf(v, v, s2);
    }
    atomicAdd(&stats[col], s);
    atomicAdd(&stats[C + col], s2);
}

__global__ void k_coef(const float* __restrict__ stats, const float* __restrict__ w,
                       const float* __restrict__ b, const float* __restrict__ ms,
                       float* __restrict__ AB, int rows) {
    int C = blockDim.x, col = threadIdx.x;
    float inv = 1.f / (float)rows;
    float mean = stats[col] * inv;
    float c = mean * ms[col];
    float var = stats[C + col] * inv - 2.f * c * mean + c * c;
    float A = w[col] * rsqrtf(var + GEPS);
    AB[col] = A;
    AB[C + col] = b[col] - A * c;
}

__global__ void k_normelu(float* __restrict__ x, const float* __restrict__ AB, int Cm1, int C,
                          size_t total4) {
    size_t i = (size_t)blockIdx.x * blockDim.x + threadIdx.x;
    size_t stride = (size_t)gridDim.x * blockDim.x;
    float4* x4 = (float4*)x;
    for (; i < total4; i += stride) {
        float4 v = x4[i];
        int col = (int)((i * 4) & (size_t)Cm1);
        float4 a = *(const float4*)&AB[col];
        float4 b = *(const float4*)&AB[C + col];
        v.x = fmaf(a.x, v.x, b.x);
        v.y = fmaf(a.y, v.y, b.y);
        v.z = fmaf(a.z, v.z, b.z);
        v.w = fmaf(a.w, v.w, b.w);
        v.x = (v.x > 0.f) ? v.x : expm1f(v.x);
        v.y = (v.y > 0.f) ? v.y : expm1f(v.y);
        v.z = (v.z > 0.f) ? v.z : expm1f(v.z);
        v.w = (v.w > 0.f) ? v.w : expm1f(v.w);
        x4[i] = v;
    }
}

// ---------------- GEMM2: [N,256] x [256,128] -> [N,128], fp32, LDS-tiled ----------------
__global__ __launch_bounds__(256) void k_gemm2(const float* __restrict__ X,
                                               const float* __restrict__ W,
                                               float* __restrict__ Y, int Nn) {
    __shared__ float ws[64][128];
    __shared__ float xs[32][68];
    int t = threadIdx.x;
    int cg = t & 31, rg = t >> 5;  // 32 col-groups x 8 row-groups
    int n0 = blockIdx.x * 32;
    float acc[4][4] = {};
    for (int kc = 0; kc < 256; kc += 64) {
#pragma unroll
        for (int i = 0; i < 32; ++i) {
            int elem = t + i * 256;
            int k = elem >> 7, c = elem & 127;
            ws[k][c] = W[(size_t)(kc + k) * 128 + c];
        }
#pragma unroll
        for (int i = 0; i < 8; ++i) {
            int elem = t + i * 256;
            int r = elem >> 6, k = elem & 63;
            int row = n0 + r;
            xs[r][k] = (row < Nn) ? X[(size_t)row * 256 + kc + k] : 0.f;
        }
        __syncthreads();
#pragma unroll
        for (int k4 = 0; k4 < 64; k4 += 4) {
            float4 wv0 = *(const float4*)&ws[k4 + 0][4 * cg];
            float4 wv1 = *(const float4*)&ws[k4 + 1][4 * cg];
            float4 wv2 = *(const float4*)&ws[k4 + 2][4 * cg];
            float4 wv3 = *(const float4*)&ws[k4 + 3][4 * cg];
#pragma unroll
            for (int r = 0; r < 4; ++r) {
                float4 xv = *(const float4*)&xs[4 * rg + r][k4];
                acc[r][0] = fmaf(xv.x, wv0.x, fmaf(xv.y, wv1.x, fmaf(xv.z, wv2.x, fmaf(xv.w, wv3.x, acc[r][0]))));
                acc[r][1] = fmaf(xv.x, wv0.y, fmaf(xv.y, wv1.y, fmaf(xv.z, wv2.y, fmaf(xv.w, wv3.y, acc[r][1]))));
                acc[r][2] = fmaf(xv.x, wv0.z, fmaf(xv.y, wv1.z, fmaf(xv.z, wv2.z, fmaf(xv.w, wv3.z, acc[r][2]))));
                acc[r][3] = fmaf(xv.x, wv0.w, fmaf(xv.y, wv1.w, fmaf(xv.z, wv2.w, fmaf(xv.w, wv3.w, acc[r][3]))));
            }
        }
        __syncthreads();
    }
#pragma unroll
    for (int r = 0; r < 4; ++r) {
        int row = n0 + 4 * rg + r;
        if (row < Nn) {
            float4 o = make_float4(acc[r][0], acc[r][1], acc[r][2], acc[r][3]);
            *(float4*)&Y[(size_t)row * 128 + 4 * cg] = o;
        }
    }
}

// ---------------- classifier: [N,128] x [128,13] + bc ----------------
__global__ void k_cls(const float* __restrict__ X, const float* __restrict__ Wc,
                      const float* __restrict__ bc, float* __restrict__ out, int Nn) {
    __shared__ float wS[128 * 13];
    __shared__ float bS[13];
    int t = threadIdx.x;
    for (int i = t; i < 128 * 13; i += 256) wS[i] = Wc[i];
    if (t < 13) bS[t] = bc[t];
    __syncthreads();
    int idx = blockIdx.x * 256 + t;
    if (idx >= Nn * 13) return;
    int n = idx / 13, j = idx - n * 13;
    const float* xr = X + (size_t)n * 128;
    float acc = bS[j];
#pragma unroll 8
    for (int k = 0; k < 128; ++k) acc = fmaf(xr[k], wS[k * 13 + j], acc);
    out[idx] = acc;
}

extern "C" void kernel_launch(void* const* d_in, const int* in_sizes, int n_in, void* d_out,
                              int out_size, void* d_ws, size_t ws_size, hipStream_t stream) {
    const float* x = (const float*)d_in[0];
    const int* edge_index = (const int*)d_in[1];
    const float* edge_attr = (const float*)d_in[2];
    const float* W1 = (const float*)d_in[3];
    const float* We1 = (const float*)d_in[4];
    const float* as1 = (const float*)d_in[5];
    const float* ad1 = (const float*)d_in[6];
    const float* ae1 = (const float*)d_in[7];
    const float* b1 = (const float*)d_in[8];
    const float* gn1_w = (const float*)d_in[9];
    const float* gn1_b = (const float*)d_in[10];
    const float* gn1_ms = (const float*)d_in[11];
    const float* W2 = (const float*)d_in[12];
    const float* We2 = (const float*)d_in[13];
    const float* as2 = (const float*)d_in[14];
    const float* ad2 = (const float*)d_in[15];
    const float* ae2 = (const float*)d_in[16];
    const float* b2 = (const float*)d_in[17];
    const float* gn2_w = (const float*)d_in[18];
    const float* gn2_b = (const float*)d_in[19];
    const float* gn2_ms = (const float*)d_in[20];
    const float* Wc = (const float*)d_in[21];
    const float* bc = (const float*)d_in[22];

    const int N = in_sizes[0] / 3;
    const int E = in_sizes[1] / 2;
    const int* srcv = edge_index;
    const int* dstv = edge_index + E;

    // ---- workspace carve (256B-aligned chunks) ----
    char* w = (char*)d_ws;
    auto carve = [&](size_t elems) -> void* {
        void* p = (void*)w;
        w += ((elems * 4 + 255) / 256) * 256;
        return p;
    };
    // zeroed region first:
    int* deg = (int*)carve(N);
    int* cursor = (int*)carve(N);
    float* ea_sum = (float*)carve(2);
    float* statsA = (float*)carve(512);  // Sx[256], Sx2[256]
    float* statsB = (float*)carve(256);  // Sx[128], Sx2[128]
    char* zero_end = w;
    // not zeroed:
    int* row_ptr = (int*)carve(N + 1);
    int* bsum = (int*)carve(1024);
    int* eidv = (int*)carve(E);
    float* C1 = (float*)carve(8);
    float* lE1 = (float*)carve(4);
    float* C2 = (float*)carve(4);
    float* lE2 = (float*)carve(2);
    float* AB1 = (float*)carve(512);
    float* AB2 = (float*)carve(256);
    float* al_s1 = (float*)carve((size_t)N * 4);
    float* al_d1 = (float*)carve((size_t)N * 4);
    float* al_s2 = (float*)carve((size_t)N * 2);
    float* al_d2 = (float*)carve((size_t)N * 2);
    float* bufA = (float*)carve((size_t)N * 256);  // h1, later h2
    float* bufB = (float*)carve((size_t)N * 256);  // out1/h1n, later out2

    hipMemsetAsync(deg, 0, (size_t)(zero_end - (char*)deg), stream);

    const int nb1 = (N + 1023) / 1024;

    k_ea_sum<<<256, 256, 0, stream>>>(edge_attr, ea_sum, E);
    k_deg<<<(E + 255) / 256, 256, 0, stream>>>(dstv, deg, E);
    k_scan1<<<nb1, 1024, 0, stream>>>(deg, row_ptr, bsum, N);
    k_scan2<<<1, 1024, 0, stream>>>(bsum, nb1);
    k_scan3<<<nb1, 1024, 0, stream>>>(row_ptr, bsum, N);
    k_scatter<<<(E + 255) / 256, 256, 0, stream>>>(dstv, row_ptr, cursor, eidv, E);
    k_consts<<<1, 256, 0, stream>>>(We1, ae1, We2, ae2, ea_sum, E, C1, lE1, C2, lE2);

    // ---- layer 1 ----
    k_l1<<<N, 256, 0, stream>>>(x, W1, as1, ad1, bufA, al_s1, al_d1);
    k_agg<4><<<N, 256, 0, stream>>>(bufA, al_s1, al_d1, srcv, edge_attr, row_ptr, eidv, C1, lE1,
                                    b1, bufB);
    k_stats<<<512, 256, 0, stream>>>(bufB, statsA, N);
    k_coef<<<1, 256, 0, stream>>>(statsA, gn1_w, gn1_b, gn1_ms, AB1, N);
    k_normelu<<<1024, 256, 0, stream>>>(bufB, AB1, 255, 256, (size_t)N * 64);

    // ---- layer 2 ----
    k_gemm2<<<(N + 31) / 32, 256, 0, stream>>>(bufB, W2, bufA, N);
    k_al2<<<N, 128, 0, stream>>>(bufA, as2, ad2, al_s2, al_d2);
    k_agg<2><<<N, 128, 0, stream>>>(bufA, al_s2, al_d2, srcv, edge_attr, row_ptr, eidv, C2, lE2,
                                    b2, bufB);
    k_stats<<<512, 128, 0, stream>>>(bufB, statsB, N);
    k_coef<<<1, 128, 0, stream>>>(statsB, gn2_w, gn2_b, gn2_ms, AB2, N);
    k_normelu<<<1024, 256, 0, stream>>>(bufB, AB2, 127, 128, (size_t)N * 32);

    // ---- classifier ----
    k_cls<<<(N * 13 + 255) / 256, 256, 0, stream>>>(bufB, Wc, bc, (float*)d_out, N);
}

// Round 2
// 616.503 us; speedup vs baseline: 1.2329x; 1.2329x over previous
//
#include <hip/hip_runtime.h>
#include <math.h>

#define NEG_SLOPE 0.2f
#define GEPS 1e-5f

__device__ __forceinline__ float wave_reduce_sum(float v) {
#pragma unroll
    for (int o = 32; o > 0; o >>= 1) v += __shfl_down(v, o);
    return v;
}

__device__ __forceinline__ ushort f2bf(float f) {
    union { float f; unsigned int i; } c;
    c.f = f;
    unsigned int b = c.i;
    b += 0x7fffu + ((b >> 16) & 1u);
    return (ushort)(b >> 16);
}

__device__ __forceinline__ float2 unpack_bf2(unsigned int u) {
    union { unsigned int i; float f; } a, b;
    a.i = u << 16;            // low ushort -> even col
    b.i = u & 0xffff0000u;    // high ushort -> odd col
    return make_float2(a.f, b.f);
}

__device__ __forceinline__ unsigned int pack_bf2(float lo, float hi) {
    return (unsigned int)f2bf(lo) | ((unsigned int)f2bf(hi) << 16);
}

// ---------------- edge_attr column sums ----------------
__global__ void k_ea_sum(const float* __restrict__ ea, float* __restrict__ ea_sum, int E) {
    const float2* ea2 = (const float2*)ea;
    float s0 = 0.f, s1 = 0.f;
    int stride = gridDim.x * blockDim.x;
    for (int e = blockIdx.x * blockDim.x + threadIdx.x; e < E; e += stride) {
        float2 v = ea2[e];
        s0 += v.x; s1 += v.y;
    }
    s0 = wave_reduce_sum(s0);
    s1 = wave_reduce_sum(s1);
    if ((threadIdx.x & 63) == 0) {
        atomicAdd(&ea_sum[0], s0);
        atomicAdd(&ea_sum[1], s1);
    }
}

// ---------------- CSR build ----------------
__global__ void k_deg(const int* __restrict__ dst, int* __restrict__ deg, int E) {
    int e = blockIdx.x * blockDim.x + threadIdx.x;
    if (e < E) atomicAdd(&deg[dst[e]], 1);
}

__global__ void k_scan1(const int* __restrict__ deg, int* __restrict__ row_ptr,
                        int* __restrict__ bsum, int N) {
    __shared__ int tmp[1024];
    int tid = threadIdx.x;
    int i = blockIdx.x * 1024 + tid;
    int v = (i < N) ? deg[i] : 0;
    tmp[tid] = v;
    __syncthreads();
#pragma unroll
    for (int off = 1; off < 1024; off <<= 1) {
        int t = (tid >= off) ? tmp[tid - off] : 0;
        __syncthreads();
        tmp[tid] += t;
        __syncthreads();
    }
    if (i < N) row_ptr[i + 1] = tmp[tid];
    if (tid == 1023) bsum[blockIdx.x] = tmp[1023];
}

__global__ void k_scan2(int* __restrict__ bsum, int nb) {
    __shared__ int tmp[1024];
    int tid = threadIdx.x;
    int v = (tid < nb) ? bsum[tid] : 0;
    tmp[tid] = v;
    __syncthreads();
#pragma unroll
    for (int off = 1; off < 1024; off <<= 1) {
        int t = (tid >= off) ? tmp[tid - off] : 0;
        __syncthreads();
        tmp[tid] += t;
        __syncthreads();
    }
    if (tid < nb) bsum[tid] = tmp[tid] - v;  // exclusive
}

__global__ void k_scan3(int* __restrict__ row_ptr, const int* __restrict__ bsum, int N) {
    int i = blockIdx.x * 1024 + threadIdx.x;
    if (i == 0) row_ptr[0] = 0;
    if (i < N) row_ptr[i + 1] += bsum[blockIdx.x];
}

// scatter edge -> CSR slot, materializing {src, ea.x, ea.y} as float4
__global__ void k_scatter(const int* __restrict__ dst, const int* __restrict__ src,
                          const float* __restrict__ ea, const int* __restrict__ row_ptr,
                          int* __restrict__ cursor, float4* __restrict__ csr, int E) {
    int e = blockIdx.x * blockDim.x + threadIdx.x;
    if (e >= E) return;
    int d = dst[e];
    int pos = atomicAdd(&cursor[d], 1);
    float2 v = ((const float2*)ea)[e];
    float4 o;
    o.x = __int_as_float(src[e]);
    o.y = v.x;
    o.z = v.y;
    o.w = 0.f;
    csr[row_ptr[d] + pos] = o;
}

// ---------------- attention-edge constants ----------------
__global__ void k_consts(const float* __restrict__ We1, const float* __restrict__ ae1,
                         const float* __restrict__ We2, const float* __restrict__ ae2,
                         const float* __restrict__ ea_sum, int E,
                         float* __restrict__ C1, float* __restrict__ lE1,
                         float* __restrict__ C2, float* __restrict__ lE2) {
    int t = threadIdx.x, h = t >> 6, lane = t & 63;
    float p0 = We1[t] * ae1[t];
    float p1 = We1[256 + t] * ae1[t];
    p0 = wave_reduce_sum(p0);
    p1 = wave_reduce_sum(p1);
    if (lane == 0) { C1[h] = p0; C1[4 + h] = p1; }
    if (t < 128) {
        float q0 = We2[t] * ae2[t];
        float q1 = We2[128 + t] * ae2[t];
        q0 = wave_reduce_sum(q0);
        q1 = wave_reduce_sum(q1);
        if (lane == 0) { C2[h] = q0; C2[2 + h] = q1; }
    }
    __syncthreads();
    float m0 = ea_sum[0] / (float)E, m1 = ea_sum[1] / (float)E;
    if (t < 4) lE1[t] = m0 * C1[t] + m1 * C1[4 + t];
    if (t < 2) lE2[t] = m0 * C2[t] + m1 * C2[2 + t];
}

// ---------------- layer-1 transform: x[N,3] @ W1[3,256] -> h1 bf16, + attn dots ----------------
// block = 128 (2 waves), 2 cols/thread, grid = N
__global__ void k_l1(const float* __restrict__ x, const float* __restrict__ W1,
                     const float* __restrict__ as1, const float* __restrict__ ad1,
                     ushort* __restrict__ h1, float* __restrict__ al_s,
                     float* __restrict__ al_d) {
    int n = blockIdx.x, t = threadIdx.x, lane = t & 63;
    int c0 = 2 * t;
    float x0 = x[3 * n], x1 = x[3 * n + 1], x2 = x[3 * n + 2];
    float h0 = fmaf(x0, W1[c0], fmaf(x1, W1[256 + c0], x2 * W1[512 + c0]));
    float h1v = fmaf(x0, W1[c0 + 1], fmaf(x1, W1[257 + c0], x2 * W1[513 + c0]));
    ((unsigned int*)h1)[n * 128 + t] = pack_bf2(h0, h1v);
    float ps = h0 * as1[c0] + h1v * as1[c0 + 1];
    float pd = h0 * ad1[c0] + h1v * ad1[c0 + 1];
#pragma unroll
    for (int o = 16; o > 0; o >>= 1) {  // reduce within 32-lane half (one head)
        ps += __shfl_xor(ps, o);
        pd += __shfl_xor(pd, o);
    }
    if ((lane & 31) == 0) {
        int h = c0 >> 6;
        al_s[n * 4 + h] = ps;
        al_d[n * 4 + h] = pd;
    }
}

// ---------------- layer-1 aggregation: 2 waves/node, wave covers 2 heads, bf16 gather ----------
__global__ void k_agg1(const ushort* __restrict__ h1, const float* __restrict__ al_s,
                       const float* __restrict__ al_d, const int* __restrict__ row_ptr,
                       const float4* __restrict__ csr, const float* __restrict__ C,
                       const float* __restrict__ loopE, const float* __restrict__ bias,
                       float* __restrict__ out, int N) {
    int u = threadIdx.x >> 7;            // node sub-index within block
    int n = blockIdx.x * 2 + u;
    if (n >= N) return;
    int tw = threadIdx.x & 127;
    int w = tw >> 6, lane = tw & 63;
    int c0 = 128 * w + 2 * lane;         // even col in [0,256)
    int h = c0 >> 6;                     // head 0..3
    const unsigned int* h1u = (const unsigned int*)h1;
    float aln_d = al_d[n * 4 + h];
    float C0 = C[h], C1v = C[4 + h];
    float lself = al_s[n * 4 + h] + aln_d + loopE[h];
    lself = (lself > 0.f) ? lself : lself * NEG_SLOPE;
    float m = lself, s = 1.f;
    float2 acc = unpack_bf2(h1u[n * 128 + (c0 >> 1)]);
    int i0 = row_ptr[n], i1 = row_ptr[n + 1];
    for (int i = i0; i < i1; ++i) {
        float4 me = csr[i];
        int sn = __float_as_int(me.x);
        float l = al_s[sn * 4 + h] + aln_d + me.y * C0 + me.z * C1v;
        l = (l > 0.f) ? l : l * NEG_SLOPE;
        float2 hv = unpack_bf2(h1u[sn * 128 + (c0 >> 1)]);
        float mn = fmaxf(m, l);
        float sc = __expf(m - mn), wgt = __expf(l - mn);
        s = s * sc + wgt;
        acc.x = acc.x * sc + wgt * hv.x;
        acc.y = acc.y * sc + wgt * hv.y;
        m = mn;
    }
    float inv = 1.f / s;
    float2 o;
    o.x = acc.x * inv + bias[c0];
    o.y = acc.y * inv + bias[c0 + 1];
    ((float2*)out)[n * 128 + (c0 >> 1)] = o;
}

// ---------------- layer-2 attn dots from bf16 h2: 4 nodes/block ----------------
__global__ void k_al2(const ushort* __restrict__ h2, const float* __restrict__ as_,
                      const float* __restrict__ ad_, float* __restrict__ al_s,
                      float* __restrict__ al_d, int N) {
    int u = threadIdx.x >> 6;
    int n = blockIdx.x * 4 + u;
    if (n >= N) return;
    int lane = threadIdx.x & 63;
    int c0 = 2 * lane;
    float2 f = unpack_bf2(((const unsigned int*)h2)[n * 64 + lane]);
    float ps = f.x * as_[c0] + f.y * as_[c0 + 1];
    float pd = f.x * ad_[c0] + f.y * ad_[c0 + 1];
#pragma unroll
    for (int o = 16; o > 0; o >>= 1) {
        ps += __shfl_xor(ps, o);
        pd += __shfl_xor(pd, o);
    }
    if ((lane & 31) == 0) {
        int h = lane >> 5;
        al_s[n * 2 + h] = ps;
        al_d[n * 2 + h] = pd;
    }
}

// ---------------- layer-2 aggregation: 1 wave/node covers both heads ----------------
__global__ void k_agg2(const ushort* __restrict__ h2, const float* __restrict__ al_s,
                       const float* __restrict__ al_d, const int* __restrict__ row_ptr,
                       const float4* __restrict__ csr, const float* __restrict__ C,
                       const float* __restrict__ loopE, const float* __restrict__ bias,
                       float* __restrict__ out, int N) {
    int u = threadIdx.x >> 6;
    int n = blockIdx.x * 4 + u;
    if (n >= N) return;
    int lane = threadIdx.x & 63;
    int c0 = 2 * lane;
    int h = lane >> 5;
    const unsigned int* h2u = (const unsigned int*)h2;
    float aln_d = al_d[n * 2 + h];
    float C0 = C[h], C1v = C[2 + h];
    float lself = al_s[n * 2 + h] + aln_d + loopE[h];
    lself = (lself > 0.f) ? lself : lself * NEG_SLOPE;
    float m = lself, s = 1.f;
    float2 acc = unpack_bf2(h2u[n * 64 + lane]);
    int i0 = row_ptr[n], i1 = row_ptr[n + 1];
    for (int i = i0; i < i1; ++i) {
        float4 me = csr[i];
        int sn = __float_as_int(me.x);
        float l = al_s[sn * 2 + h] + aln_d + me.y * C0 + me.z * C1v;
        l = (l > 0.f) ? l : l * NEG_SLOPE;
        float2 hv = unpack_bf2(h2u[sn * 64 + lane]);
        float mn = fmaxf(m, l);
        float sc = __expf(m - mn), wgt = __expf(l - mn);
        s = s * sc + wgt;
        acc.x = acc.x * sc + wgt * hv.x;
        acc.y = acc.y * sc + wgt * hv.y;
        m = mn;
    }
    float inv = 1.f / s;
    float2 o;
    o.x = acc.x * inv + bias[c0];
    o.y = acc.y * inv + bias[c0 + 1];
    ((float2*)out)[n * 64 + lane] = o;
}

// ---------------- GraphNorm: column stats ----------------
__global__ void k_stats(const float* __restrict__ x, float* __restrict__ stats, int rows) {
    int C = blockDim.x, col = threadIdx.x;
    float s = 0.f, s2 = 0.f;
    for (int r = blockIdx.x; r < rows; r += gridDim.x) {
        float v = x[(size_t)r * C + col];
        s += v;
        s2 = fmaf(v, v, s2);
    }
    atomicAdd(&stats[col], s);
    atomicAdd(&stats[C + col], s2);
}

__global__ void k_coef(const float* __restrict__ stats, const float* __restrict__ w,
                       const float* __restrict__ b, const float* __restrict__ ms,
                       float* __restrict__ AB, int rows) {
    int C = blockDim.x, col = threadIdx.x;
    float inv = 1.f / (float)rows;
    float mean = stats[col] * inv;
    float c = mean * ms[col];
    float var = stats[C + col] * inv - 2.f * c * mean + c * c;
    float A = w[col] * rsqrtf(var + GEPS);
    AB[col] = A;
    AB[C + col] = b[col] - A * c;
}

// ---------------- GEMM2 with fused GraphNorm+ELU on X-load; writes bf16 h2 ----------------
__global__ __launch_bounds__(256) void k_gemm2(const float* __restrict__ X,
                                               const float* __restrict__ AB,
                                               const float* __restrict__ W,
                                               ushort* __restrict__ H2, int Nn) {
    __shared__ float ws[64][128];
    __shared__ float xs[32][68];
    int t = threadIdx.x;
    int cg = t & 31, rg = t >> 5;
    int n0 = blockIdx.x * 32;
    float acc[4][4] = {};
    for (int kc = 0; kc < 256; kc += 64) {
#pragma unroll
        for (int i = 0; i < 32; ++i) {
            int elem = t + i * 256;
            int k = elem >> 7, c = elem & 127;
            ws[k][c] = W[(size_t)(kc + k) * 128 + c];
        }
#pragma unroll
        for (int i = 0; i < 8; ++i) {
            int elem = t + i * 256;
            int r = elem >> 6, k = elem & 63;
            int row = n0 + r, col = kc + k;
            float v = 0.f;
            if (row < Nn) {
                v = fmaf(AB[col], X[(size_t)row * 256 + col], AB[256 + col]);
                v = (v > 0.f) ? v : expm1f(v);
            }
            xs[r][k] = v;
        }
        __syncthreads();
#pragma unroll
        for (int k4 = 0; k4 < 64; k4 += 4) {
            float4 wv0 = *(const float4*)&ws[k4 + 0][4 * cg];
            float4 wv1 = *(const float4*)&ws[k4 + 1][4 * cg];
            float4 wv2 = *(const float4*)&ws[k4 + 2][4 * cg];
            float4 wv3 = *(const float4*)&ws[k4 + 3][4 * cg];
#pragma unroll
            for (int r = 0; r < 4; ++r) {
                float4 xv = *(const float4*)&xs[4 * rg + r][k4];
                acc[r][0] = fmaf(xv.x, wv0.x, fmaf(xv.y, wv1.x, fmaf(xv.z, wv2.x, fmaf(xv.w, wv3.x, acc[r][0]))));
                acc[r][1] = fmaf(xv.x, wv0.y, fmaf(xv.y, wv1.y, fmaf(xv.z, wv2.y, fmaf(xv.w, wv3.y, acc[r][1]))));
                acc[r][2] = fmaf(xv.x, wv0.z, fmaf(xv.y, wv1.z, fmaf(xv.z, wv2.z, fmaf(xv.w, wv3.z, acc[r][2]))));
                acc[r][3] = fmaf(xv.x, wv0.w, fmaf(xv.y, wv1.w, fmaf(xv.z, wv2.w, fmaf(xv.w, wv3.w, acc[r][3]))));
            }
        }
        __syncthreads();
    }
#pragma unroll
    for (int r = 0; r < 4; ++r) {
        int row = n0 + 4 * rg + r;
        if (row < Nn) {
            unsigned int p0 = pack_bf2(acc[r][0], acc[r][1]);
            unsigned int p1 = pack_bf2(acc[r][2], acc[r][3]);
            unsigned int* dst = (unsigned int*)H2 + (size_t)row * 64 + 2 * cg;
            dst[0] = p0;
            dst[1] = p1;
        }
    }
}

// ---------------- classifier with fused GraphNorm+ELU: 16 rows/block via LDS ----------------
__global__ __launch_bounds__(256) void k_cls(const float* __restrict__ X,
                                             const float* __restrict__ AB,
                                             const float* __restrict__ Wc,
                                             const float* __restrict__ bc,
                                             float* __restrict__ out, int Nn) {
    __shared__ __align__(16) float ls[16 * 132];
    __shared__ __align__(16) float wT[13 * 132];
    __shared__ float bS[13];
    int t = threadIdx.x;
    int n0 = blockIdx.x * 16;
    for (int i = t; i < 128 * 13; i += 256) {
        int k = i / 13, j = i - k * 13;
        wT[j * 132 + k] = Wc[i];
    }
    if (t < 13) bS[t] = bc[t];
    for (int idx = t; idx < 16 * 128; idx += 256) {
        int r = idx >> 7, k = idx & 127;
        int row = n0 + r;
        float v = 0.f;
        if (row < Nn) {
            v = fmaf(AB[k], X[(size_t)row * 128 + k], AB[128 + k]);
            v = (v > 0.f) ? v : expm1f(v);
        }
        ls[r * 132 + k] = v;
    }
    __syncthreads();
    if (t < 208) {
        int r = t / 13, j = t - r * 13;
        int row = n0 + r;
        if (row < Nn) {
            float acc = bS[j];
            const float* lr = &ls[r * 132];
            const float* wr = &wT[j * 132];
#pragma unroll 8
            for (int k = 0; k < 128; k += 4) {
                float4 a = *(const float4*)&lr[k];
                float4 b = *(const float4*)&wr[k];
                acc = fmaf(a.x, b.x, fmaf(a.y, b.y, fmaf(a.z, b.z, fmaf(a.w, b.w, acc))));
            }
            out[(size_t)row * 13 + j] = acc;
        }
    }
}

extern "C" void kernel_launch(void* const* d_in, const int* in_sizes, int n_in, void* d_out,
                              int out_size, void* d_ws, size_t ws_size, hipStream_t stream) {
    const float* x = (const float*)d_in[0];
    const int* edge_index = (const int*)d_in[1];
    const float* edge_attr = (const float*)d_in[2];
    const float* W1 = (const float*)d_in[3];
    const float* We1 = (const float*)d_in[4];
    const float* as1 = (const float*)d_in[5];
    const float* ad1 = (const float*)d_in[6];
    const float* ae1 = (const float*)d_in[7];
    const float* b1 = (const float*)d_in[8];
    const float* gn1_w = (const float*)d_in[9];
    const float* gn1_b = (const float*)d_in[10];
    const float* gn1_ms = (const float*)d_in[11];
    const float* W2 = (const float*)d_in[12];
    const float* We2 = (const float*)d_in[13];
    const float* as2 = (const float*)d_in[14];
    const float* ad2 = (const float*)d_in[15];
    const float* ae2 = (const float*)d_in[16];
    const float* b2 = (const float*)d_in[17];
    const float* gn2_w = (const float*)d_in[18];
    const float* gn2_b = (const float*)d_in[19];
    const float* gn2_ms = (const float*)d_in[20];
    const float* Wc = (const float*)d_in[21];
    const float* bc = (const float*)d_in[22];

    const int N = in_sizes[0] / 3;
    const int E = in_sizes[1] / 2;
    const int* srcv = edge_index;
    const int* dstv = edge_index + E;

    // ---- workspace carve (256B-aligned, byte-based) ----
    char* w = (char*)d_ws;
    auto carveB = [&](size_t bytes) -> void* {
        void* p = (void*)w;
        w += ((bytes + 255) / 256) * 256;
        return p;
    };
    // zeroed region first:
    int* deg = (int*)carveB((size_t)N * 4);
    int* cursor = (int*)carveB((size_t)N * 4);
    float* ea_sum = (float*)carveB(8);
    float* statsA = (float*)carveB(512 * 4);
    float* statsB = (float*)carveB(256 * 4);
    char* zero_end = w;
    // not zeroed:
    int* row_ptr = (int*)carveB((size_t)(N + 1) * 4);
    int* bsum = (int*)carveB(1024 * 4);
    float4* csr = (float4*)carveB((size_t)E * 16);
    float* C1 = (float*)carveB(8 * 4);
    float* lE1 = (float*)carveB(4 * 4);
    float* C2 = (float*)carveB(4 * 4);
    float* lE2 = (float*)carveB(2 * 4);
    float* AB1 = (float*)carveB(512 * 4);
    float* AB2 = (float*)carveB(256 * 4);
    float* al_s1 = (float*)carveB((size_t)N * 4 * 4);
    float* al_d1 = (float*)carveB((size_t)N * 4 * 4);
    float* al_s2 = (float*)carveB((size_t)N * 2 * 4);
    float* al_d2 = (float*)carveB((size_t)N * 2 * 4);
    ushort* h1b = (ushort*)carveB((size_t)N * 256 * 2);  // bf16 h1; later aliased by out2
    ushort* h2b = (ushort*)carveB((size_t)N * 128 * 2);  // bf16 h2
    float* out1 = (float*)carveB((size_t)N * 256 * 4);   // fp32 layer-1 output
    float* out2 = (float*)h1b;                           // fp32 layer-2 output (h1b dead by then)

    hipMemsetAsync(deg, 0, (size_t)(zero_end - (char*)deg), stream);

    const int nb1 = (N + 1023) / 1024;

    k_ea_sum<<<256, 256, 0, stream>>>(edge_attr, ea_sum, E);
    k_deg<<<(E + 255) / 256, 256, 0, stream>>>(dstv, deg, E);
    k_scan1<<<nb1, 1024, 0, stream>>>(deg, row_ptr, bsum, N);
    k_scan2<<<1, 1024, 0, stream>>>(bsum, nb1);
    k_scan3<<<nb1, 1024, 0, stream>>>(row_ptr, bsum, N);
    k_scatter<<<(E + 255) / 256, 256, 0, stream>>>(dstv, srcv, edge_attr, row_ptr, cursor, csr, E);
    k_consts<<<1, 256, 0, stream>>>(We1, ae1, We2, ae2, ea_sum, E, C1, lE1, C2, lE2);

    // ---- layer 1 ----
    k_l1<<<N, 128, 0, stream>>>(x, W1, as1, ad1, h1b, al_s1, al_d1);
    k_agg1<<<(N + 1) / 2, 256, 0, stream>>>(h1b, al_s1, al_d1, row_ptr, csr, C1, lE1, b1, out1, N);
    k_stats<<<512, 256, 0, stream>>>(out1, statsA, N);
    k_coef<<<1, 256, 0, stream>>>(statsA, gn1_w, gn1_b, gn1_ms, AB1, N);

    // ---- layer 2 (norm+ELU fused into gemm2 X-load) ----
    k_gemm2<<<(N + 31) / 32, 256, 0, stream>>>(out1, AB1, W2, h2b, N);
    k_al2<<<(N + 3) / 4, 256, 0, stream>>>(h2b, as2, ad2, al_s2, al_d2, N);
    k_agg2<<<(N + 3) / 4, 256, 0, stream>>>(h2b, al_s2, al_d2, row_ptr, csr, C2, lE2, b2, out2, N);
    k_stats<<<512, 128, 0, stream>>>(out2, statsB, N);
    k_coef<<<1, 128, 0, stream>>>(statsB, gn2_w, gn2_b, gn2_ms, AB2, N);

    // ---- classifier (norm+ELU fused) ----
    k_cls<<<(N + 15) / 16, 256, 0, stream>>>(out2, AB2, Wc, bc, (float*)d_out, N);
}

// Round 3
// 486.282 us; speedup vs baseline: 1.5630x; 1.2678x over previous
//
#include <hip/hip_runtime.h>
#include <math.h>

#define NEG_SLOPE 0.2f
#define GEPS 1e-5f

typedef __attribute__((ext_vector_type(8))) short short8;
typedef __attribute__((ext_vector_type(4))) float floatx4;

__device__ __forceinline__ float wave_reduce_sum(float v) {
#pragma unroll
    for (int o = 32; o > 0; o >>= 1) v += __shfl_down(v, o);
    return v;
}

__device__ __forceinline__ ushort f2bf(float f) {
    union { float f; unsigned int i; } c;
    c.f = f;
    unsigned int b = c.i;
    b += 0x7fffu + ((b >> 16) & 1u);
    return (ushort)(b >> 16);
}

__device__ __forceinline__ float2 unpack_bf2(unsigned int u) {
    union { unsigned int i; float f; } a, b;
    a.i = u << 16;            // low ushort -> even col
    b.i = u & 0xffff0000u;    // high ushort -> odd col
    return make_float2(a.f, b.f);
}

__device__ __forceinline__ unsigned int pack_bf2(float lo, float hi) {
    return (unsigned int)f2bf(lo) | ((unsigned int)f2bf(hi) << 16);
}

// ---------------- edge_attr column sums ----------------
__global__ void k_ea_sum(const float* __restrict__ ea, float* __restrict__ ea_sum, int E) {
    const float2* ea2 = (const float2*)ea;
    float s0 = 0.f, s1 = 0.f;
    int stride = gridDim.x * blockDim.x;
    for (int e = blockIdx.x * blockDim.x + threadIdx.x; e < E; e += stride) {
        float2 v = ea2[e];
        s0 += v.x; s1 += v.y;
    }
    s0 = wave_reduce_sum(s0);
    s1 = wave_reduce_sum(s1);
    if ((threadIdx.x & 63) == 0) {
        atomicAdd(&ea_sum[0], s0);
        atomicAdd(&ea_sum[1], s1);
    }
}

// ---------------- CSR build ----------------
__global__ void k_deg(const int* __restrict__ dst, int* __restrict__ deg, int E) {
    int e = blockIdx.x * blockDim.x + threadIdx.x;
    if (e < E) atomicAdd(&deg[dst[e]], 1);
}

__global__ void k_scan1(const int* __restrict__ deg, int* __restrict__ row_ptr,
                        int* __restrict__ bsum, int N) {
    __shared__ int tmp[1024];
    int tid = threadIdx.x;
    int i = blockIdx.x * 1024 + tid;
    int v = (i < N) ? deg[i] : 0;
    tmp[tid] = v;
    __syncthreads();
#pragma unroll
    for (int off = 1; off < 1024; off <<= 1) {
        int t = (tid >= off) ? tmp[tid - off] : 0;
        __syncthreads();
        tmp[tid] += t;
        __syncthreads();
    }
    if (i < N) row_ptr[i + 1] = tmp[tid];
    if (tid == 1023) bsum[blockIdx.x] = tmp[1023];
}

__global__ void k_scan2(int* __restrict__ bsum, int nb) {
    __shared__ int tmp[1024];
    int tid = threadIdx.x;
    int v = (tid < nb) ? bsum[tid] : 0;
    tmp[tid] = v;
    __syncthreads();
#pragma unroll
    for (int off = 1; off < 1024; off <<= 1) {
        int t = (tid >= off) ? tmp[tid - off] : 0;
        __syncthreads();
        tmp[tid] += t;
        __syncthreads();
    }
    if (tid < nb) bsum[tid] = tmp[tid] - v;  // exclusive
}

__global__ void k_scan3(int* __restrict__ row_ptr, const int* __restrict__ bsum, int N) {
    int i = blockIdx.x * 1024 + threadIdx.x;
    if (i == 0) row_ptr[0] = 0;
    if (i < N) row_ptr[i + 1] += bsum[blockIdx.x];
}

// scatter edge -> CSR slot, materializing {src, ea.x, ea.y} as float4
__global__ void k_scatter(const int* __restrict__ dst, const int* __restrict__ src,
                          const float* __restrict__ ea, const int* __restrict__ row_ptr,
                          int* __restrict__ cursor, float4* __restrict__ csr, int E) {
    int e = blockIdx.x * blockDim.x + threadIdx.x;
    if (e >= E) return;
    int d = dst[e];
    int pos = atomicAdd(&cursor[d], 1);
    float2 v = ((const float2*)ea)[e];
    float4 o;
    o.x = __int_as_float(src[e]);
    o.y = v.x;
    o.z = v.y;
    o.w = 0.f;
    csr[row_ptr[d] + pos] = o;
}

// ---------------- attention-edge constants ----------------
__global__ void k_consts(const float* __restrict__ We1, const float* __restrict__ ae1,
                         const float* __restrict__ We2, const float* __restrict__ ae2,
                         const float* __restrict__ ea_sum, int E,
                         float* __restrict__ C1, float* __restrict__ lE1,
                         float* __restrict__ C2, float* __restrict__ lE2) {
    int t = threadIdx.x, h = t >> 6, lane = t & 63;
    float p0 = We1[t] * ae1[t];
    float p1 = We1[256 + t] * ae1[t];
    p0 = wave_reduce_sum(p0);
    p1 = wave_reduce_sum(p1);
    if (lane == 0) { C1[h] = p0; C1[4 + h] = p1; }
    if (t < 128) {
        float q0 = We2[t] * ae2[t];
        float q1 = We2[128 + t] * ae2[t];
        q0 = wave_reduce_sum(q0);
        q1 = wave_reduce_sum(q1);
        if (lane == 0) { C2[h] = q0; C2[2 + h] = q1; }
    }
    __syncthreads();
    float m0 = ea_sum[0] / (float)E, m1 = ea_sum[1] / (float)E;
    if (t < 4) lE1[t] = m0 * C1[t] + m1 * C1[4 + t];
    if (t < 2) lE2[t] = m0 * C2[t] + m1 * C2[2 + t];
}

// ---------------- W2 -> bf16 MFMA B-fragment layout ----------------
// Bfrag[(c*8+kk)*64 + L] = 8 bf16: B[k0+j][n], k0 = kk*32 + (L>>4)*8, n = c*16 + (L&15)
__global__ void k_w2frag(const float* __restrict__ W2, uint4* __restrict__ Bfrag) {
    int t = blockIdx.x * 256 + threadIdx.x;  // 4096 threads
    int c = t >> 9, kk = (t >> 6) & 7, L = t & 63;
    int q = L >> 4, n = c * 16 + (L & 15);
    int k0 = kk * 32 + q * 8;
    unsigned int u0 = pack_bf2(W2[(k0 + 0) * 128 + n], W2[(k0 + 1) * 128 + n]);
    unsigned int u1 = pack_bf2(W2[(k0 + 2) * 128 + n], W2[(k0 + 3) * 128 + n]);
    unsigned int u2 = pack_bf2(W2[(k0 + 4) * 128 + n], W2[(k0 + 5) * 128 + n]);
    unsigned int u3 = pack_bf2(W2[(k0 + 6) * 128 + n], W2[(k0 + 7) * 128 + n]);
    Bfrag[t] = make_uint4(u0, u1, u2, u3);
}

// ---------------- layer-1 transform: x[N,3] @ W1[3,256] -> h1 bf16, + attn dots ----------------
__global__ void k_l1(const float* __restrict__ x, const float* __restrict__ W1,
                     const float* __restrict__ as1, const float* __restrict__ ad1,
                     ushort* __restrict__ h1, float* __restrict__ al_s,
                     float* __restrict__ al_d) {
    int n = blockIdx.x, t = threadIdx.x, lane = t & 63;
    int c0 = 2 * t;
    float x0 = x[3 * n], x1 = x[3 * n + 1], x2 = x[3 * n + 2];
    float h0 = fmaf(x0, W1[c0], fmaf(x1, W1[256 + c0], x2 * W1[512 + c0]));
    float h1v = fmaf(x0, W1[c0 + 1], fmaf(x1, W1[257 + c0], x2 * W1[513 + c0]));
    ((unsigned int*)h1)[n * 128 + t] = pack_bf2(h0, h1v);
    float ps = h0 * as1[c0] + h1v * as1[c0 + 1];
    float pd = h0 * ad1[c0] + h1v * ad1[c0 + 1];
#pragma unroll
    for (int o = 16; o > 0; o >>= 1) {
        ps += __shfl_xor(ps, o);
        pd += __shfl_xor(pd, o);
    }
    if ((lane & 31) == 0) {
        int h = c0 >> 6;
        al_s[n * 4 + h] = ps;
        al_d[n * 4 + h] = pd;
    }
}

// ---------------- layer-1 aggregation: 2 waves/node, wave covers 2 heads, bf16 gather ----------
__global__ void k_agg1(const ushort* __restrict__ h1, const float* __restrict__ al_s,
                       const float* __restrict__ al_d, const int* __restrict__ row_ptr,
                       const float4* __restrict__ csr, const float* __restrict__ C,
                       const float* __restrict__ loopE, const float* __restrict__ bias,
                       float* __restrict__ out, int N) {
    int u = threadIdx.x >> 7;
    int n = blockIdx.x * 2 + u;
    if (n >= N) return;
    int tw = threadIdx.x & 127;
    int w = tw >> 6, lane = tw & 63;
    int c0 = 128 * w + 2 * lane;
    int h = c0 >> 6;
    const unsigned int* h1u = (const unsigned int*)h1;
    float aln_d = al_d[n * 4 + h];
    float C0 = C[h], C1v = C[4 + h];
    float lself = al_s[n * 4 + h] + aln_d + loopE[h];
    lself = (lself > 0.f) ? lself : lself * NEG_SLOPE;
    float m = lself, s = 1.f;
    float2 acc = unpack_bf2(h1u[n * 128 + (c0 >> 1)]);
    int i0 = row_ptr[n], i1 = row_ptr[n + 1];
    for (int i = i0; i < i1; ++i) {
        float4 me = csr[i];
        int sn = __float_as_int(me.x);
        float l = al_s[sn * 4 + h] + aln_d + me.y * C0 + me.z * C1v;
        l = (l > 0.f) ? l : l * NEG_SLOPE;
        float2 hv = unpack_bf2(h1u[sn * 128 + (c0 >> 1)]);
        float mn = fmaxf(m, l);
        float sc = __expf(m - mn), wgt = __expf(l - mn);
        s = s * sc + wgt;
        acc.x = acc.x * sc + wgt * hv.x;
        acc.y = acc.y * sc + wgt * hv.y;
        m = mn;
    }
    float inv = 1.f / s;
    float2 o;
    o.x = acc.x * inv + bias[c0];
    o.y = acc.y * inv + bias[c0 + 1];
    ((float2*)out)[n * 128 + (c0 >> 1)] = o;
}

// ---------------- layer-2 attn dots from bf16 h2 ----------------
__global__ void k_al2(const ushort* __restrict__ h2, const float* __restrict__ as_,
                      const float* __restrict__ ad_, float* __restrict__ al_s,
                      float* __restrict__ al_d, int N) {
    int u = threadIdx.x >> 6;
    int n = blockIdx.x * 4 + u;
    if (n >= N) return;
    int lane = threadIdx.x & 63;
    int c0 = 2 * lane;
    float2 f = unpack_bf2(((const unsigned int*)h2)[n * 64 + lane]);
    float ps = f.x * as_[c0] + f.y * as_[c0 + 1];
    float pd = f.x * ad_[c0] + f.y * ad_[c0 + 1];
#pragma unroll
    for (int o = 16; o > 0; o >>= 1) {
        ps += __shfl_xor(ps, o);
        pd += __shfl_xor(pd, o);
    }
    if ((lane & 31) == 0) {
        int h = lane >> 5;
        al_s[n * 2 + h] = ps;
        al_d[n * 2 + h] = pd;
    }
}

// ---------------- layer-2 aggregation: 1 wave/node covers both heads ----------------
__global__ void k_agg2(const ushort* __restrict__ h2, const float* __restrict__ al_s,
                       const float* __restrict__ al_d, const int* __restrict__ row_ptr,
                       const float4* __restrict__ csr, const float* __restrict__ C,
                       const float* __restrict__ loopE, const float* __restrict__ bias,
                       float* __restrict__ out, int N) {
    int u = threadIdx.x >> 6;
    int n = blockIdx.x * 4 + u;
    if (n >= N) return;
    int lane = threadIdx.x & 63;
    int c0 = 2 * lane;
    int h = lane >> 5;
    const unsigned int* h2u = (const unsigned int*)h2;
    float aln_d = al_d[n * 2 + h];
    float C0 = C[h], C1v = C[2 + h];
    float lself = al_s[n * 2 + h] + aln_d + loopE[h];
    lself = (lself > 0.f) ? lself : lself * NEG_SLOPE;
    float m = lself, s = 1.f;
    float2 acc = unpack_bf2(h2u[n * 64 + lane]);
    int i0 = row_ptr[n], i1 = row_ptr[n + 1];
    for (int i = i0; i < i1; ++i) {
        float4 me = csr[i];
        int sn = __float_as_int(me.x);
        float l = al_s[sn * 2 + h] + aln_d + me.y * C0 + me.z * C1v;
        l = (l > 0.f) ? l : l * NEG_SLOPE;
        float2 hv = unpack_bf2(h2u[sn * 64 + lane]);
        float mn = fmaxf(m, l);
        float sc = __expf(m - mn), wgt = __expf(l - mn);
        s = s * sc + wgt;
        acc.x = acc.x * sc + wgt * hv.x;
        acc.y = acc.y * sc + wgt * hv.y;
        m = mn;
    }
    float inv = 1.f / s;
    float2 o;
    o.x = acc.x * inv + bias[c0];
    o.y = acc.y * inv + bias[c0 + 1];
    ((float2*)out)[n * 64 + lane] = o;
}

// ---------------- GraphNorm: column stats ----------------
__global__ void k_stats(const float* __restrict__ x, float* __restrict__ stats, int rows) {
    int C = blockDim.x, col = threadIdx.x;
    float s = 0.f, s2 = 0.f;
    for (int r = blockIdx.x; r < rows; r += gridDim.x) {
        float v = x[(size_t)r * C + col];
        s += v;
        s2 = fmaf(v, v, s2);
    }
    atomicAdd(&stats[col], s);
    atomicAdd(&stats[C + col], s2);
}

__global__ void k_coef(const float* __restrict__ stats, const float* __restrict__ w,
                       const float* __restrict__ b, const float* __restrict__ ms,
                       float* __restrict__ AB, int rows) {
    int C = blockDim.x, col = threadIdx.x;
    float inv = 1.f / (float)rows;
    float mean = stats[col] * inv;
    float c = mean * ms[col];
    float var = stats[C + col] * inv - 2.f * c * mean + c * c;
    float A = w[col] * rsqrtf(var + GEPS);
    AB[col] = A;
    AB[C + col] = b[col] - A * c;
}

// ---------------- MFMA GEMM2: ELU(norm(X)) @ W2 -> h2 bf16 ----------------
// block = 256 (4 waves), each wave owns 16 rows; no LDS.
__global__ __launch_bounds__(256) void k_gemm2_mfma(const float* __restrict__ X,
                                                    const float* __restrict__ AB,
                                                    const uint4* __restrict__ Bfrag,
                                                    ushort* __restrict__ H2, int Nn) {
    int wave = threadIdx.x >> 6, lane = threadIdx.x & 63;
    int q = lane >> 4, m = lane & 15;
    int rowbase = blockIdx.x * 64 + wave * 16;
    int row = rowbase + m;
    bool valid = row < Nn;
    floatx4 acc[8];
#pragma unroll
    for (int c = 0; c < 8; ++c) acc[c] = (floatx4){0.f, 0.f, 0.f, 0.f};
    const float* xr = X + (size_t)row * 256;
#pragma unroll
    for (int kk = 0; kk < 8; ++kk) {
        int k0 = kk * 32 + q * 8;
        float4 xa = valid ? *(const float4*)(xr + k0) : make_float4(0.f, 0.f, 0.f, 0.f);
        float4 xb = valid ? *(const float4*)(xr + k0 + 4) : make_float4(0.f, 0.f, 0.f, 0.f);
        float4 a0 = *(const float4*)(AB + k0);
        float4 a1 = *(const float4*)(AB + k0 + 4);
        float4 b0 = *(const float4*)(AB + 256 + k0);
        float4 b1 = *(const float4*)(AB + 256 + k0 + 4);
        float v0 = fmaf(a0.x, xa.x, b0.x);
        float v1 = fmaf(a0.y, xa.y, b0.y);
        float v2 = fmaf(a0.z, xa.z, b0.z);
        float v3 = fmaf(a0.w, xa.w, b0.w);
        float v4 = fmaf(a1.x, xb.x, b1.x);
        float v5 = fmaf(a1.y, xb.y, b1.y);
        float v6 = fmaf(a1.z, xb.z, b1.z);
        float v7 = fmaf(a1.w, xb.w, b1.w);
        v0 = (v0 > 0.f) ? v0 : expm1f(v0);
        v1 = (v1 > 0.f) ? v1 : expm1f(v1);
        v2 = (v2 > 0.f) ? v2 : expm1f(v2);
        v3 = (v3 > 0.f) ? v3 : expm1f(v3);
        v4 = (v4 > 0.f) ? v4 : expm1f(v4);
        v5 = (v5 > 0.f) ? v5 : expm1f(v5);
        v6 = (v6 > 0.f) ? v6 : expm1f(v6);
        v7 = (v7 > 0.f) ? v7 : expm1f(v7);
        union { short8 s; unsigned int u[4]; } af;
        af.u[0] = pack_bf2(v0, v1);
        af.u[1] = pack_bf2(v2, v3);
        af.u[2] = pack_bf2(v4, v5);
        af.u[3] = pack_bf2(v6, v7);
        const uint4* bp = Bfrag + kk * 64 + lane;
#pragma unroll
        for (int c = 0; c < 8; ++c) {
            union { short8 s; uint4 u; } bf;
            bf.u = bp[c * 8 * 64];
            acc[c] = __builtin_amdgcn_mfma_f32_16x16x32_bf16(af.s, bf.s, acc[c], 0, 0, 0);
        }
    }
    // C/D layout: col = lane&15, row-in-tile = (lane>>4)*4 + reg
#pragma unroll
    for (int r = 0; r < 4; ++r) {
        int orow = rowbase + q * 4 + r;
        if (orow < Nn) {
            ushort* op = H2 + (size_t)orow * 128 + m;
#pragma unroll
            for (int c = 0; c < 8; ++c) op[c * 16] = f2bf(acc[c][r]);
        }
    }
}

// ---------------- classifier with fused GraphNorm+ELU ----------------
__global__ __launch_bounds__(256) void k_cls(const float* __restrict__ X,
                                             const float* __restrict__ AB,
                                             const float* __restrict__ Wc,
                                             const float* __restrict__ bc,
                                             float* __restrict__ out, int Nn) {
    __shared__ __align__(16) float ls[16 * 132];
    __shared__ __align__(16) float wT[13 * 132];
    __shared__ float bS[13];
    int t = threadIdx.x;
    int n0 = blockIdx.x * 16;
    for (int i = t; i < 128 * 13; i += 256) {
        int k = i / 13, j = i - k * 13;
        wT[j * 132 + k] = Wc[i];
    }
    if (t < 13) bS[t] = bc[t];
    for (int idx = t; idx < 16 * 128; idx += 256) {
        int r = idx >> 7, k = idx & 127;
        int row = n0 + r;
        float v = 0.f;
        if (row < Nn) {
            v = fmaf(AB[k], X[(size_t)row * 128 + k], AB[128 + k]);
            v = (v > 0.f) ? v : expm1f(v);
        }
        ls[r * 132 + k] = v;
    }
    __syncthreads();
    if (t < 208) {
        int r = t / 13, j = t - r * 13;
        int row = n0 + r;
        if (row < Nn) {
            float acc = bS[j];
            const float* lr = &ls[r * 132];
            const float* wr = &wT[j * 132];
#pragma unroll 8
            for (int k = 0; k < 128; k += 4) {
                float4 a = *(const float4*)&lr[k];
                float4 b = *(const float4*)&wr[k];
                acc = fmaf(a.x, b.x, fmaf(a.y, b.y, fmaf(a.z, b.z, fmaf(a.w, b.w, acc))));
            }
            out[(size_t)row * 13 + j] = acc;
        }
    }
}

extern "C" void kernel_launch(void* const* d_in, const int* in_sizes, int n_in, void* d_out,
                              int out_size, void* d_ws, size_t ws_size, hipStream_t stream) {
    const float* x = (const float*)d_in[0];
    const int* edge_index = (const int*)d_in[1];
    const float* edge_attr = (const float*)d_in[2];
    const float* W1 = (const float*)d_in[3];
    const float* We1 = (const float*)d_in[4];
    const float* as1 = (const float*)d_in[5];
    const float* ad1 = (const float*)d_in[6];
    const float* ae1 = (const float*)d_in[7];
    const float* b1 = (const float*)d_in[8];
    const float* gn1_w = (const float*)d_in[9];
    const float* gn1_b = (const float*)d_in[10];
    const float* gn1_ms = (const float*)d_in[11];
    const float* W2 = (const float*)d_in[12];
    const float* We2 = (const float*)d_in[13];
    const float* as2 = (const float*)d_in[14];
    const float* ad2 = (const float*)d_in[15];
    const float* ae2 = (const float*)d_in[16];
    const float* b2 = (const float*)d_in[17];
    const float* gn2_w = (const float*)d_in[18];
    const float* gn2_b = (const float*)d_in[19];
    const float* gn2_ms = (const float*)d_in[20];
    const float* Wc = (const float*)d_in[21];
    const float* bc = (const float*)d_in[22];

    const int N = in_sizes[0] / 3;
    const int E = in_sizes[1] / 2;
    const int* srcv = edge_index;
    const int* dstv = edge_index + E;

    // ---- workspace carve (256B-aligned, byte-based) ----
    char* w = (char*)d_ws;
    auto carveB = [&](size_t bytes) -> void* {
        void* p = (void*)w;
        w += ((bytes + 255) / 256) * 256;
        return p;
    };
    // zeroed region first:
    int* deg = (int*)carveB((size_t)N * 4);
    int* cursor = (int*)carveB((size_t)N * 4);
    float* ea_sum = (float*)carveB(8);
    float* statsA = (float*)carveB(512 * 4);
    float* statsB = (float*)carveB(256 * 4);
    char* zero_end = w;
    // not zeroed:
    int* row_ptr = (int*)carveB((size_t)(N + 1) * 4);
    int* bsum = (int*)carveB(1024 * 4);
    float4* csr = (float4*)carveB((size_t)E * 16);
    float* C1 = (float*)carveB(8 * 4);
    float* lE1 = (float*)carveB(4 * 4);
    float* C2 = (float*)carveB(4 * 4);
    float* lE2 = (float*)carveB(2 * 4);
    float* AB1 = (float*)carveB(512 * 4);
    float* AB2 = (float*)carveB(256 * 4);
    uint4* Bfrag = (uint4*)carveB(4096 * 16);
    float* al_s1 = (float*)carveB((size_t)N * 4 * 4);
    float* al_d1 = (float*)carveB((size_t)N * 4 * 4);
    float* al_s2 = (float*)carveB((size_t)N * 2 * 4);
    float* al_d2 = (float*)carveB((size_t)N * 2 * 4);
    ushort* h1b = (ushort*)carveB((size_t)N * 256 * 2);  // bf16 h1; later aliased by out2
    ushort* h2b = (ushort*)carveB((size_t)N * 128 * 2);  // bf16 h2
    float* out1 = (float*)carveB((size_t)N * 256 * 4);   // fp32 layer-1 output
    float* out2 = (float*)h1b;                           // fp32 layer-2 output (h1b dead by then)

    hipMemsetAsync(deg, 0, (size_t)(zero_end - (char*)deg), stream);

    const int nb1 = (N + 1023) / 1024;

    k_ea_sum<<<256, 256, 0, stream>>>(edge_attr, ea_sum, E);
    k_deg<<<(E + 255) / 256, 256, 0, stream>>>(dstv, deg, E);
    k_scan1<<<nb1, 1024, 0, stream>>>(deg, row_ptr, bsum, N);
    k_scan2<<<1, 1024, 0, stream>>>(bsum, nb1);
    k_scan3<<<nb1, 1024, 0, stream>>>(row_ptr, bsum, N);
    k_scatter<<<(E + 255) / 256, 256, 0, stream>>>(dstv, srcv, edge_attr, row_ptr, cursor, csr, E);
    k_consts<<<1, 256, 0, stream>>>(We1, ae1, We2, ae2, ea_sum, E, C1, lE1, C2, lE2);
    k_w2frag<<<16, 256, 0, stream>>>(W2, Bfrag);

    // ---- layer 1 ----
    k_l1<<<N, 128, 0, stream>>>(x, W1, as1, ad1, h1b, al_s1, al_d1);
    k_agg1<<<(N + 1) / 2, 256, 0, stream>>>(h1b, al_s1, al_d1, row_ptr, csr, C1, lE1, b1, out1, N);
    k_stats<<<512, 256, 0, stream>>>(out1, statsA, N);
    k_coef<<<1, 256, 0, stream>>>(statsA, gn1_w, gn1_b, gn1_ms, AB1, N);

    // ---- layer 2 (norm+ELU fused into MFMA GEMM A-load) ----
    k_gemm2_mfma<<<(N + 63) / 64, 256, 0, stream>>>(out1, AB1, Bfrag, h2b, N);
    k_al2<<<(N + 3) / 4, 256, 0, stream>>>(h2b, as2, ad2, al_s2, al_d2, N);
    k_agg2<<<(N + 3) / 4, 256, 0, stream>>>(h2b, al_s2, al_d2, row_ptr, csr, C2, lE2, b2, out2, N);
    k_stats<<<512, 128, 0, stream>>>(out2, statsB, N);
    k_coef<<<1, 128, 0, stream>>>(statsB, gn2_w, gn2_b, gn2_ms, AB2, N);

    // ---- classifier (norm+ELU fused) ----
    k_cls<<<(N + 15) / 16, 256, 0, stream>>>(out2, AB2, Wc, bc, (float*)d_out, N);
}

// Round 4
// 463.301 us; speedup vs baseline: 1.6406x; 1.0496x over previous
//
#include <hip/hip_runtime.h>
#include <math.h>

#define NEG_SLOPE 0.2f
#define GEPS 1e-5f

typedef __attribute__((ext_vector_type(8))) short short8;
typedef __attribute__((ext_vector_type(4))) float floatx4;

__device__ __forceinline__ float wave_reduce_sum(float v) {
#pragma unroll
    for (int o = 32; o > 0; o >>= 1) v += __shfl_down(v, o);
    return v;
}

__device__ __forceinline__ ushort f2bf(float f) {
    union { float f; unsigned int i; } c;
    c.f = f;
    unsigned int b = c.i;
    b += 0x7fffu + ((b >> 16) & 1u);
    return (ushort)(b >> 16);
}

__device__ __forceinline__ float2 unpack_bf2(unsigned int u) {
    union { unsigned int i; float f; } a, b;
    a.i = u << 16;            // low ushort -> even col
    b.i = u & 0xffff0000u;    // high ushort -> odd col
    return make_float2(a.f, b.f);
}

__device__ __forceinline__ unsigned int pack_bf2(float lo, float hi) {
    return (unsigned int)f2bf(lo) | ((unsigned int)f2bf(hi) << 16);
}

// ---------------- edge_attr column sums ----------------
__global__ void k_ea_sum(const float* __restrict__ ea, float* __restrict__ ea_sum, int E) {
    const float2* ea2 = (const float2*)ea;
    float s0 = 0.f, s1 = 0.f;
    int stride = gridDim.x * blockDim.x;
    for (int e = blockIdx.x * blockDim.x + threadIdx.x; e < E; e += stride) {
        float2 v = ea2[e];
        s0 += v.x; s1 += v.y;
    }
    s0 = wave_reduce_sum(s0);
    s1 = wave_reduce_sum(s1);
    if ((threadIdx.x & 63) == 0) {
        atomicAdd(&ea_sum[0], s0);
        atomicAdd(&ea_sum[1], s1);
    }
}

// ---------------- CSR build ----------------
__global__ void k_deg(const int* __restrict__ dst, int* __restrict__ deg, int E) {
    int e = blockIdx.x * blockDim.x + threadIdx.x;
    if (e < E) atomicAdd(&deg[dst[e]], 1);
}

__global__ void k_scan1(const int* __restrict__ deg, int* __restrict__ row_ptr,
                        int* __restrict__ bsum, int N) {
    __shared__ int tmp[1024];
    int tid = threadIdx.x;
    int i = blockIdx.x * 1024 + tid;
    int v = (i < N) ? deg[i] : 0;
    tmp[tid] = v;
    __syncthreads();
#pragma unroll
    for (int off = 1; off < 1024; off <<= 1) {
        int t = (tid >= off) ? tmp[tid - off] : 0;
        __syncthreads();
        tmp[tid] += t;
        __syncthreads();
    }
    if (i < N) row_ptr[i + 1] = tmp[tid];
    if (tid == 1023) bsum[blockIdx.x] = tmp[1023];
}

__global__ void k_scan2(int* __restrict__ bsum, int nb) {
    __shared__ int tmp[1024];
    int tid = threadIdx.x;
    int v = (tid < nb) ? bsum[tid] : 0;
    tmp[tid] = v;
    __syncthreads();
#pragma unroll
    for (int off = 1; off < 1024; off <<= 1) {
        int t = (tid >= off) ? tmp[tid - off] : 0;
        __syncthreads();
        tmp[tid] += t;
        __syncthreads();
    }
    if (tid < nb) bsum[tid] = tmp[tid] - v;  // exclusive
}

__global__ void k_scan3(int* __restrict__ row_ptr, const int* __restrict__ bsum, int N) {
    int i = blockIdx.x * 1024 + threadIdx.x;
    if (i == 0) row_ptr[0] = 0;
    if (i < N) row_ptr[i + 1] += bsum[blockIdx.x];
}

// scatter edge -> CSR slot, materializing {src, ea.x, ea.y} as float4
__global__ void k_scatter(const int* __restrict__ dst, const int* __restrict__ src,
                          const float* __restrict__ ea, const int* __restrict__ row_ptr,
                          int* __restrict__ cursor, float4* __restrict__ csr, int E) {
    int e = blockIdx.x * blockDim.x + threadIdx.x;
    if (e >= E) return;
    int d = dst[e];
    int pos = atomicAdd(&cursor[d], 1);
    float2 v = ((const float2*)ea)[e];
    float4 o;
    o.x = __int_as_float(src[e]);
    o.y = v.x;
    o.z = v.y;
    o.w = 0.f;
    csr[row_ptr[d] + pos] = o;
}

// ---------------- attention-edge constants ----------------
__global__ void k_consts(const float* __restrict__ We1, const float* __restrict__ ae1,
                         const float* __restrict__ We2, const float* __restrict__ ae2,
                         const float* __restrict__ ea_sum, int E,
                         float* __restrict__ C1, float* __restrict__ lE1,
                         float* __restrict__ C2, float* __restrict__ lE2) {
    int t = threadIdx.x, h = t >> 6, lane = t & 63;
    float p0 = We1[t] * ae1[t];
    float p1 = We1[256 + t] * ae1[t];
    p0 = wave_reduce_sum(p0);
    p1 = wave_reduce_sum(p1);
    if (lane == 0) { C1[h] = p0; C1[4 + h] = p1; }
    if (t < 128) {
        float q0 = We2[t] * ae2[t];
        float q1 = We2[128 + t] * ae2[t];
        q0 = wave_reduce_sum(q0);
        q1 = wave_reduce_sum(q1);
        if (lane == 0) { C2[h] = q0; C2[2 + h] = q1; }
    }
    __syncthreads();
    float m0 = ea_sum[0] / (float)E, m1 = ea_sum[1] / (float)E;
    if (t < 4) lE1[t] = m0 * C1[t] + m1 * C1[4 + t];
    if (t < 2) lE2[t] = m0 * C2[t] + m1 * C2[2 + t];
}

// ---------------- W2 -> bf16 MFMA B-fragment layout ----------------
__global__ void k_w2frag(const float* __restrict__ W2, uint4* __restrict__ Bfrag) {
    int t = blockIdx.x * 256 + threadIdx.x;  // 4096 threads
    int c = t >> 9, kk = (t >> 6) & 7, L = t & 63;
    int q = L >> 4, n = c * 16 + (L & 15);
    int k0 = kk * 32 + q * 8;
    unsigned int u0 = pack_bf2(W2[(k0 + 0) * 128 + n], W2[(k0 + 1) * 128 + n]);
    unsigned int u1 = pack_bf2(W2[(k0 + 2) * 128 + n], W2[(k0 + 3) * 128 + n]);
    unsigned int u2 = pack_bf2(W2[(k0 + 4) * 128 + n], W2[(k0 + 5) * 128 + n]);
    unsigned int u3 = pack_bf2(W2[(k0 + 6) * 128 + n], W2[(k0 + 7) * 128 + n]);
    Bfrag[t] = make_uint4(u0, u1, u2, u3);
}

// ---------------- layer-1 transform: x[N,3] @ W1[3,256] -> h1 bf16, + attn dots ----------------
__global__ void k_l1(const float* __restrict__ x, const float* __restrict__ W1,
                     const float* __restrict__ as1, const float* __restrict__ ad1,
                     ushort* __restrict__ h1, float* __restrict__ al_s,
                     float* __restrict__ al_d) {
    int n = blockIdx.x, t = threadIdx.x, lane = t & 63;
    int c0 = 2 * t;
    float x0 = x[3 * n], x1 = x[3 * n + 1], x2 = x[3 * n + 2];
    float h0 = fmaf(x0, W1[c0], fmaf(x1, W1[256 + c0], x2 * W1[512 + c0]));
    float h1v = fmaf(x0, W1[c0 + 1], fmaf(x1, W1[257 + c0], x2 * W1[513 + c0]));
    ((unsigned int*)h1)[n * 128 + t] = pack_bf2(h0, h1v);
    float ps = h0 * as1[c0] + h1v * as1[c0 + 1];
    float pd = h0 * ad1[c0] + h1v * ad1[c0 + 1];
#pragma unroll
    for (int o = 16; o > 0; o >>= 1) {
        ps += __shfl_xor(ps, o);
        pd += __shfl_xor(pd, o);
    }
    if ((lane & 31) == 0) {
        int h = c0 >> 6;
        al_s[n * 4 + h] = ps;
        al_d[n * 4 + h] = pd;
    }
}

// ---------------- edge-parallel partial-logit fill (layer 1, H=4) ----------------
// P0[e] = {src, p_h0, p_h1, 0}, P1[e] = {src, p_h2, p_h3, 0}; p = al_s[src,h] + ea.C
__global__ void k_fill4(const float4* __restrict__ csr, const float* __restrict__ al_s,
                        const float* __restrict__ C, float4* __restrict__ P0,
                        float4* __restrict__ P1, int E) {
    int e = blockIdx.x * 256 + threadIdx.x;
    if (e >= E) return;
    float4 me = csr[e];
    int sn = __float_as_int(me.x);
    float4 as = *(const float4*)(al_s + 4 * (size_t)sn);
    float p0 = as.x + me.y * C[0] + me.z * C[4];
    float p1 = as.y + me.y * C[1] + me.z * C[5];
    float p2 = as.z + me.y * C[2] + me.z * C[6];
    float p3 = as.w + me.y * C[3] + me.z * C[7];
    P0[e] = make_float4(me.x, p0, p1, 0.f);
    P1[e] = make_float4(me.x, p2, p3, 0.f);
}

// ---------------- edge-parallel partial-logit fill (layer 2, H=2) ----------------
__global__ void k_fill2(const float4* __restrict__ csr, const float* __restrict__ al_s,
                        const float* __restrict__ C, float4* __restrict__ P0, int E) {
    int e = blockIdx.x * 256 + threadIdx.x;
    if (e >= E) return;
    float4 me = csr[e];
    int sn = __float_as_int(me.x);
    float2 as = *(const float2*)(al_s + 2 * (size_t)sn);
    float p0 = as.x + me.y * C[0] + me.z * C[2];
    float p1 = as.y + me.y * C[1] + me.z * C[3];
    P0[e] = make_float4(me.x, p0, p1, 0.f);
}

// ---------------- layer-1 aggregation: pipelined, 1 wave per (node, head-pair) ----------------
__global__ void k_agg1(const ushort* __restrict__ h1, const float* __restrict__ al_s,
                       const float* __restrict__ al_d, const int* __restrict__ row_ptr,
                       const float4* __restrict__ P0, const float4* __restrict__ P1,
                       const float* __restrict__ loopE, const float* __restrict__ bias,
                       ushort* __restrict__ out, int N) {
    int u = threadIdx.x >> 7;
    int n = blockIdx.x * 2 + u;
    if (n >= N) return;
    int tw = threadIdx.x & 127;
    int w = tw >> 6, lane = tw & 63;
    int c0 = 128 * w + 2 * lane;
    int h = c0 >> 6;
    bool hi = (lane >= 32);
    int half = 64 * w + lane;
    const unsigned int* h1u = (const unsigned int*)h1;
    float aln_d = al_d[n * 4 + h];
    float lself = al_s[n * 4 + h] + aln_d + loopE[h];
    lself = (lself > 0.f) ? lself : lself * NEG_SLOPE;
    float m = lself, s = 1.f;
    float2 acc = unpack_bf2(h1u[(size_t)n * 128 + half]);
    int i0 = row_ptr[n];
    int cnt = row_ptr[n + 1] - i0;
    const float4* cp = ((w == 0) ? P0 : P1) + i0;
    float4 meA, meB;
    unsigned int hvA = 0;
    if (cnt > 0) {
        meA = cp[0];
        hvA = h1u[(size_t)__float_as_int(meA.x) * 128 + half];
        meB = cp[(cnt > 1) ? 1 : 0];
    }
    for (int i = 1; i < cnt; ++i) {
        int j = (i + 1 < cnt) ? (i + 1) : (cnt - 1);
        float4 meC = cp[j];
        unsigned int hvB = h1u[(size_t)__float_as_int(meB.x) * 128 + half];
        float p = hi ? meA.z : meA.y;
        float l = p + aln_d;
        l = (l > 0.f) ? l : l * NEG_SLOPE;
        float2 hv = unpack_bf2(hvA);
        float mn = fmaxf(m, l);
        float sc = __expf(m - mn), wgt = __expf(l - mn);
        s = s * sc + wgt;
        acc.x = acc.x * sc + wgt * hv.x;
        acc.y = acc.y * sc + wgt * hv.y;
        m = mn;
        meA = meB;
        hvA = hvB;
        meB = meC;
    }
    if (cnt > 0) {
        float p = hi ? meA.z : meA.y;
        float l = p + aln_d;
        l = (l > 0.f) ? l : l * NEG_SLOPE;
        float2 hv = unpack_bf2(hvA);
        float mn = fmaxf(m, l);
        float sc = __expf(m - mn), wgt = __expf(l - mn);
        s = s * sc + wgt;
        acc.x = acc.x * sc + wgt * hv.x;
        acc.y = acc.y * sc + wgt * hv.y;
        m = mn;
    }
    float inv = 1.f / s;
    unsigned int o = pack_bf2(acc.x * inv + bias[c0], acc.y * inv + bias[c0 + 1]);
    ((unsigned int*)out)[(size_t)n * 128 + half] = o;
}

// ---------------- layer-2 attn dots from bf16 h2 ----------------
__global__ void k_al2(const ushort* __restrict__ h2, const float* __restrict__ as_,
                      const float* __restrict__ ad_, float* __restrict__ al_s,
                      float* __restrict__ al_d, int N) {
    int u = threadIdx.x >> 6;
    int n = blockIdx.x * 4 + u;
    if (n >= N) return;
    int lane = threadIdx.x & 63;
    int c0 = 2 * lane;
    float2 f = unpack_bf2(((const unsigned int*)h2)[n * 64 + lane]);
    float ps = f.x * as_[c0] + f.y * as_[c0 + 1];
    float pd = f.x * ad_[c0] + f.y * ad_[c0 + 1];
#pragma unroll
    for (int o = 16; o > 0; o >>= 1) {
        ps += __shfl_xor(ps, o);
        pd += __shfl_xor(pd, o);
    }
    if ((lane & 31) == 0) {
        int h = lane >> 5;
        al_s[n * 2 + h] = ps;
        al_d[n * 2 + h] = pd;
    }
}

// ---------------- layer-2 aggregation: pipelined, 1 wave per node ----------------
__global__ void k_agg2(const ushort* __restrict__ h2, const float* __restrict__ al_s,
                       const float* __restrict__ al_d, const int* __restrict__ row_ptr,
                       const float4* __restrict__ P0, const float* __restrict__ loopE,
                       const float* __restrict__ bias, ushort* __restrict__ out, int N) {
    int u = threadIdx.x >> 6;
    int n = blockIdx.x * 4 + u;
    if (n >= N) return;
    int lane = threadIdx.x & 63;
    int c0 = 2 * lane;
    int h = lane >> 5;
    bool hi = (lane >= 32);
    const unsigned int* h2u = (const unsigned int*)h2;
    float aln_d = al_d[n * 2 + h];
    float lself = al_s[n * 2 + h] + aln_d + loopE[h];
    lself = (lself > 0.f) ? lself : lself * NEG_SLOPE;
    float m = lself, s = 1.f;
    float2 acc = unpack_bf2(h2u[(size_t)n * 64 + lane]);
    int i0 = row_ptr[n];
    int cnt = row_ptr[n + 1] - i0;
    const float4* cp = P0 + i0;
    float4 meA, meB;
    unsigned int hvA = 0;
    if (cnt > 0) {
        meA = cp[0];
        hvA = h2u[(size_t)__float_as_int(meA.x) * 64 + lane];
        meB = cp[(cnt > 1) ? 1 : 0];
    }
    for (int i = 1; i < cnt; ++i) {
        int j = (i + 1 < cnt) ? (i + 1) : (cnt - 1);
        float4 meC = cp[j];
        unsigned int hvB = h2u[(size_t)__float_as_int(meB.x) * 64 + lane];
        float p = hi ? meA.z : meA.y;
        float l = p + aln_d;
        l = (l > 0.f) ? l : l * NEG_SLOPE;
        float2 hv = unpack_bf2(hvA);
        float mn = fmaxf(m, l);
        float sc = __expf(m - mn), wgt = __expf(l - mn);
        s = s * sc + wgt;
        acc.x = acc.x * sc + wgt * hv.x;
        acc.y = acc.y * sc + wgt * hv.y;
        m = mn;
        meA = meB;
        hvA = hvB;
        meB = meC;
    }
    if (cnt > 0) {
        float p = hi ? meA.z : meA.y;
        float l = p + aln_d;
        l = (l > 0.f) ? l : l * NEG_SLOPE;
        float2 hv = unpack_bf2(hvA);
        float mn = fmaxf(m, l);
        float sc = __expf(m - mn), wgt = __expf(l - mn);
        s = s * sc + wgt;
        acc.x = acc.x * sc + wgt * hv.x;
        acc.y = acc.y * sc + wgt * hv.y;
        m = mn;
    }
    float inv = 1.f / s;
    unsigned int o = pack_bf2(acc.x * inv + bias[c0], acc.y * inv + bias[c0 + 1]);
    ((unsigned int*)out)[(size_t)n * 64 + lane] = o;
}

// ---------------- GraphNorm column stats from bf16 input ----------------
// blockDim = C/2 threads; each thread owns 2 adjacent cols.
__global__ void k_stats_bf(const ushort* __restrict__ x, float* __restrict__ stats, int rows,
                           int C) {
    int C2 = C >> 1;
    int t = threadIdx.x;
    const unsigned int* xu = (const unsigned int*)x;
    float s0 = 0.f, s1 = 0.f, q0 = 0.f, q1 = 0.f;
    for (int r = blockIdx.x; r < rows; r += gridDim.x) {
        float2 v = unpack_bf2(xu[(size_t)r * C2 + t]);
        s0 += v.x;
        s1 += v.y;
        q0 = fmaf(v.x, v.x, q0);
        q1 = fmaf(v.y, v.y, q1);
    }
    atomicAdd(&stats[2 * t], s0);
    atomicAdd(&stats[2 * t + 1], s1);
    atomicAdd(&stats[C + 2 * t], q0);
    atomicAdd(&stats[C + 2 * t + 1], q1);
}

__global__ void k_coef(const float* __restrict__ stats, const float* __restrict__ w,
                       const float* __restrict__ b, const float* __restrict__ ms,
                       float* __restrict__ AB, int rows) {
    int C = blockDim.x, col = threadIdx.x;
    float inv = 1.f / (float)rows;
    float mean = stats[col] * inv;
    float c = mean * ms[col];
    float var = stats[C + col] * inv - 2.f * c * mean + c * c;
    float A = w[col] * rsqrtf(var + GEPS);
    AB[col] = A;
    AB[C + col] = b[col] - A * c;
}

// ---------------- MFMA GEMM2: ELU(norm(X_bf16)) @ W2 -> h2 bf16 ----------------
__global__ __launch_bounds__(256) void k_gemm2_mfma(const ushort* __restrict__ X,
                                                    const float* __restrict__ AB,
                                                    const uint4* __restrict__ Bfrag,
                                                    ushort* __restrict__ H2, int Nn) {
    int wave = threadIdx.x >> 6, lane = threadIdx.x & 63;
    int q = lane >> 4, m = lane & 15;
    int rowbase = blockIdx.x * 64 + wave * 16;
    int row = rowbase + m;
    bool valid = row < Nn;
    floatx4 acc[8];
#pragma unroll
    for (int c = 0; c < 8; ++c) acc[c] = (floatx4){0.f, 0.f, 0.f, 0.f};
    const uint4* xr4 = (const uint4*)((const unsigned int*)X + (size_t)row * 128);
#pragma unroll
    for (int kk = 0; kk < 8; ++kk) {
        int k0 = kk * 32 + q * 8;
        uint4 xu = valid ? xr4[k0 >> 3] : make_uint4(0, 0, 0, 0);
        float2 x01 = unpack_bf2(xu.x);
        float2 x23 = unpack_bf2(xu.y);
        float2 x45 = unpack_bf2(xu.z);
        float2 x67 = unpack_bf2(xu.w);
        float4 a0 = *(const float4*)(AB + k0);
        float4 a1 = *(const float4*)(AB + k0 + 4);
        float4 b0 = *(const float4*)(AB + 256 + k0);
        float4 b1 = *(const float4*)(AB + 256 + k0 + 4);
        float v0 = fmaf(a0.x, x01.x, b0.x);
        float v1 = fmaf(a0.y, x01.y, b0.y);
        float v2 = fmaf(a0.z, x23.x, b0.z);
        float v3 = fmaf(a0.w, x23.y, b0.w);
        float v4 = fmaf(a1.x, x45.x, b1.x);
        float v5 = fmaf(a1.y, x45.y, b1.y);
        float v6 = fmaf(a1.z, x67.x, b1.z);
        float v7 = fmaf(a1.w, x67.y, b1.w);
        v0 = (v0 > 0.f) ? v0 : expm1f(v0);
        v1 = (v1 > 0.f) ? v1 : expm1f(v1);
        v2 = (v2 > 0.f) ? v2 : expm1f(v2);
        v3 = (v3 > 0.f) ? v3 : expm1f(v3);
        v4 = (v4 > 0.f) ? v4 : expm1f(v4);
        v5 = (v5 > 0.f) ? v5 : expm1f(v5);
        v6 = (v6 > 0.f) ? v6 : expm1f(v6);
        v7 = (v7 > 0.f) ? v7 : expm1f(v7);
        union { short8 s; unsigned int u[4]; } af;
        af.u[0] = pack_bf2(v0, v1);
        af.u[1] = pack_bf2(v2, v3);
        af.u[2] = pack_bf2(v4, v5);
        af.u[3] = pack_bf2(v6, v7);
        const uint4* bp = Bfrag + kk * 64 + lane;
#pragma unroll
        for (int c = 0; c < 8; ++c) {
            union { short8 s; uint4 u; } bf;
            bf.u = bp[c * 8 * 64];
            acc[c] = __builtin_amdgcn_mfma_f32_16x16x32_bf16(af.s, bf.s, acc[c], 0, 0, 0);
        }
    }
#pragma unroll
    for (int r = 0; r < 4; ++r) {
        int orow = rowbase + q * 4 + r;
        if (orow < Nn) {
            ushort* op = H2 + (size_t)orow * 128 + m;
#pragma unroll
            for (int c = 0; c < 8; ++c) op[c * 16] = f2bf(acc[c][r]);
        }
    }
}

// ---------------- classifier with fused GraphNorm+ELU, bf16 input ----------------
__global__ __launch_bounds__(256) void k_cls(const ushort* __restrict__ X,
                                             const float* __restrict__ AB,
                                             const float* __restrict__ Wc,
                                             const float* __restrict__ bc,
                                             float* __restrict__ out, int Nn) {
    __shared__ __align__(16) float ls[16 * 132];
    __shared__ __align__(16) float wT[13 * 132];
    __shared__ float bS[13];
    int t = threadIdx.x;
    int n0 = blockIdx.x * 16;
    for (int i = t; i < 128 * 13; i += 256) {
        int k = i / 13, j = i - k * 13;
        wT[j * 132 + k] = Wc[i];
    }
    if (t < 13) bS[t] = bc[t];
    const unsigned int* xu = (const unsigned int*)X;
    for (int idx = t; idx < 16 * 64; idx += 256) {
        int r = idx >> 6, ku = idx & 63;
        int row = n0 + r;
        float vx = 0.f, vy = 0.f;
        if (row < Nn) {
            float2 v = unpack_bf2(xu[(size_t)row * 64 + ku]);
            int k = 2 * ku;
            vx = fmaf(AB[k], v.x, AB[128 + k]);
            vy = fmaf(AB[k + 1], v.y, AB[128 + k + 1]);
            vx = (vx > 0.f) ? vx : expm1f(vx);
            vy = (vy > 0.f) ? vy : expm1f(vy);
        }
        ls[r * 132 + 2 * ku] = vx;
        ls[r * 132 + 2 * ku + 1] = vy;
    }
    __syncthreads();
    if (t < 208) {
        int r = t / 13, j = t - r * 13;
        int row = n0 + r;
        if (row < Nn) {
            float acc = bS[j];
            const float* lr = &ls[r * 132];
            const float* wr = &wT[j * 132];
#pragma unroll 8
            for (int k = 0; k < 128; k += 4) {
                float4 a = *(const float4*)&lr[k];
                float4 b = *(const float4*)&wr[k];
                acc = fmaf(a.x, b.x, fmaf(a.y, b.y, fmaf(a.z, b.z, fmaf(a.w, b.w, acc))));
            }
            out[(size_t)row * 13 + j] = acc;
        }
    }
}

extern "C" void kernel_launch(void* const* d_in, const int* in_sizes, int n_in, void* d_out,
                              int out_size, void* d_ws, size_t ws_size, hipStream_t stream) {
    const float* x = (const float*)d_in[0];
    const int* edge_index = (const int*)d_in[1];
    const float* edge_attr = (const float*)d_in[2];
    const float* W1 = (const float*)d_in[3];
    const float* We1 = (const float*)d_in[4];
    const float* as1 = (const float*)d_in[5];
    const float* ad1 = (const float*)d_in[6];
    const float* ae1 = (const float*)d_in[7];
    const float* b1 = (const float*)d_in[8];
    const float* gn1_w = (const float*)d_in[9];
    const float* gn1_b = (const float*)d_in[10];
    const float* gn1_ms = (const float*)d_in[11];
    const float* W2 = (const float*)d_in[12];
    const float* We2 = (const float*)d_in[13];
    const float* as2 = (const float*)d_in[14];
    const float* ad2 = (const float*)d_in[15];
    const float* ae2 = (const float*)d_in[16];
    const float* b2 = (const float*)d_in[17];
    const float* gn2_w = (const float*)d_in[18];
    const float* gn2_b = (const float*)d_in[19];
    const float* gn2_ms = (const float*)d_in[20];
    const float* Wc = (const float*)d_in[21];
    const float* bc = (const float*)d_in[22];

    const int N = in_sizes[0] / 3;
    const int E = in_sizes[1] / 2;
    const int* srcv = edge_index;
    const int* dstv = edge_index + E;

    // ---- workspace carve (256B-aligned, byte-based) ----
    char* w = (char*)d_ws;
    auto carveB = [&](size_t bytes) -> void* {
        void* p = (void*)w;
        w += ((bytes + 255) / 256) * 256;
        return p;
    };
    // zeroed region first:
    int* deg = (int*)carveB((size_t)N * 4);
    int* cursor = (int*)carveB((size_t)N * 4);
    float* ea_sum = (float*)carveB(8);
    float* statsA = (float*)carveB(512 * 4);
    float* statsB = (float*)carveB(256 * 4);
    char* zero_end = w;
    // not zeroed:
    int* row_ptr = (int*)carveB((size_t)(N + 1) * 4);
    int* bsum = (int*)carveB(1024 * 4);
    float4* csr = (float4*)carveB((size_t)E * 16);
    float4* P0f = (float4*)carveB((size_t)E * 16);
    float4* P1f = (float4*)carveB((size_t)E * 16);
    float* C1 = (float*)carveB(8 * 4);
    float* lE1 = (float*)carveB(4 * 4);
    float* C2 = (float*)carveB(4 * 4);
    float* lE2 = (float*)carveB(2 * 4);
    float* AB1 = (float*)carveB(512 * 4);
    float* AB2 = (float*)carveB(256 * 4);
    uint4* Bfrag = (uint4*)carveB(4096 * 16);
    float* al_s1 = (float*)carveB((size_t)N * 4 * 4);
    float* al_d1 = (float*)carveB((size_t)N * 4 * 4);
    float* al_s2 = (float*)carveB((size_t)N * 2 * 4);
    float* al_d2 = (float*)carveB((size_t)N * 2 * 4);
    ushort* h1b = (ushort*)carveB((size_t)N * 256 * 2);   // bf16 h1; later aliased by out2b
    ushort* h2b = (ushort*)carveB((size_t)N * 128 * 2);   // bf16 h2
    ushort* out1b = (ushort*)carveB((size_t)N * 256 * 2); // bf16 layer-1 output
    ushort* out2b = h1b;                                  // bf16 layer-2 output (h1b dead)

    hipMemsetAsync(deg, 0, (size_t)(zero_end - (char*)deg), stream);

    const int nb1 = (N + 1023) / 1024;
    const int ebl = (E + 255) / 256;

    k_ea_sum<<<256, 256, 0, stream>>>(edge_attr, ea_sum, E);
    k_deg<<<ebl, 256, 0, stream>>>(dstv, deg, E);
    k_scan1<<<nb1, 1024, 0, stream>>>(deg, row_ptr, bsum, N);
    k_scan2<<<1, 1024, 0, stream>>>(bsum, nb1);
    k_scan3<<<nb1, 1024, 0, stream>>>(row_ptr, bsum, N);
    k_scatter<<<ebl, 256, 0, stream>>>(dstv, srcv, edge_attr, row_ptr, cursor, csr, E);
    k_consts<<<1, 256, 0, stream>>>(We1, ae1, We2, ae2, ea_sum, E, C1, lE1, C2, lE2);
    k_w2frag<<<16, 256, 0, stream>>>(W2, Bfrag);

    // ---- layer 1 ----
    k_l1<<<N, 128, 0, stream>>>(x, W1, as1, ad1, h1b, al_s1, al_d1);
    k_fill4<<<ebl, 256, 0, stream>>>(csr, al_s1, C1, P0f, P1f, E);
    k_agg1<<<(N + 1) / 2, 256, 0, stream>>>(h1b, al_s1, al_d1, row_ptr, P0f, P1f, lE1, b1, out1b,
                                            N);
    k_stats_bf<<<512, 128, 0, stream>>>(out1b, statsA, N, 256);
    k_coef<<<1, 256, 0, stream>>>(statsA, gn1_w, gn1_b, gn1_ms, AB1, N);

    // ---- layer 2 (norm+ELU fused into MFMA GEMM A-load) ----
    k_gemm2_mfma<<<(N + 63) / 64, 256, 0, stream>>>(out1b, AB1, Bfrag, h2b, N);
    k_al2<<<(N + 3) / 4, 256, 0, stream>>>(h2b, as2, ad2, al_s2, al_d2, N);
    k_fill2<<<ebl, 256, 0, stream>>>(csr, al_s2, C2, P0f, E);
    k_agg2<<<(N + 3) / 4, 256, 0, stream>>>(h2b, al_s2, al_d2, row_ptr, P0f, lE2, b2, out2b, N);
    k_stats_bf<<<512, 64, 0, stream>>>(out2b, statsB, N, 128);
    k_coef<<<1, 128, 0, stream>>>(statsB, gn2_w, gn2_b, gn2_ms, AB2, N);

    // ---- classifier (norm+ELU fused) ----
    k_cls<<<(N + 15) / 16, 256, 0, stream>>>(out2b, AB2, Wc, bc, (float*)d_out, N);
}